// Round 9
// baseline (45.337 us; speedup 1.0000x reference)
//
#include <hip/hip_runtime.h>
#include <float.h>

typedef float float2v __attribute__((ext_vector_type(2)));
typedef float float4v __attribute__((ext_vector_type(4)));

// Problem constants (fixed by the reference setup_inputs()).
#define N_BATCH 4
#define P1 8192
#define P2 8192
#define D 3

#define CHUNK 128                  // targets staged in LDS per block
#define NCHUNK (P2 / CHUNK)        // 64
#define RSRC 4                     // source points per thread (low VGPR!)
#define TPB 256
#define SRC_PER_BLK (TPB * RSRC)   // 1024
#define NSB (N_BATCH * P1 / SRC_PER_BLK)  // 32 source blocks (global)
#define NMIN (N_BATCH * P1)        // 32768 per-source mins

// Main pass: block (sb, c) computes, for its 1024 sources and its 128-target
// chunk, min over targets of (y^2 - 2*x.y) with v_pk_fma_f32. SoA LDS tile.
// KEY CHANGE vs R8: RSRC=4 + launch_bounds(256,8) => VGPR<=64 => 8 blocks/CU
// = 32 waves/CU (2x all previous rounds). Race-free store to ws[c][s].
__global__ __launch_bounds__(TPB, 8) void chamfer_main(
        const float* __restrict__ src,
        const float* __restrict__ tgt,
        float* __restrict__ ws,
        float* __restrict__ out) {
    const int bid = blockIdx.x;
    const int c   = bid & (NCHUNK - 1);   // target chunk 0..63
    const int sb  = bid >> 6;             // global source block 0..31
    const int n   = sb >> 3;              // batch (8 source blocks per batch)
    const int t   = threadIdx.x;

    if (bid == 0 && t == 0) out[0] = 0.0f;

    // SoA target tile: [0..127]=-2x, [128..255]=-2y, [256..383]=-2z,
    // [384..511]=|y|^2.
    __shared__ __align__(16) float sT[4 * CHUNK];

    if (t < CHUNK) {
        const int j = c * CHUNK + t;
        const float* p = tgt + ((size_t)n * P2 + j) * D;
        const float y0 = p[0], y1 = p[1], y2 = p[2];
        sT[t]             = -2.0f * y0;
        sT[CHUNK + t]     = -2.0f * y1;
        sT[2 * CHUNK + t] = -2.0f * y2;
        sT[3 * CHUNK + t] = y0 * y0 + y1 * y1 + y2 * y2;
    }
    __syncthreads();

    // Per-thread sources: packed broadcast {x,x} for v_pk_fma_f32.
    float2v bx0[RSRC], bx1[RSRC], bx2[RSRC];
    float m[RSRC];
#pragma unroll
    for (int i = 0; i < RSRC; ++i) {
        const int s = sb * SRC_PER_BLK + i * TPB + t;
        const float* p = src + (size_t)s * D;
        bx0[i] = (float2v){p[0], p[0]};
        bx1[i] = (float2v){p[1], p[1]};
        bx2[i] = (float2v){p[2], p[2]};
        m[i] = FLT_MAX;
    }

    // Each step: 4 ds_read_b128 (one 4-target quad per component), then
    // 4 sources x 2 pk-pairs x (3 v_pk_fma_f32 + 1 v_min3_f32) = 32 VALU.
#pragma unroll 4
    for (int step = 0; step < CHUNK / 4; ++step) {
        const int fb = step * 4;
        const float4v X = *(const float4v*)&sT[fb];
        const float4v Y = *(const float4v*)&sT[CHUNK + fb];
        const float4v Z = *(const float4v*)&sT[2 * CHUNK + fb];
        const float4v W = *(const float4v*)&sT[3 * CHUNK + fb];
#pragma unroll
        for (int i = 0; i < RSRC; ++i) {
            float2v d;
            d = __builtin_elementwise_fma(bx0[i], X.xy, W.xy);
            d = __builtin_elementwise_fma(bx1[i], Y.xy, d);
            d = __builtin_elementwise_fma(bx2[i], Z.xy, d);
            m[i] = fminf(fminf(m[i], d.x), d.y);   // -> v_min3_f32
            d = __builtin_elementwise_fma(bx0[i], X.zw, W.zw);
            d = __builtin_elementwise_fma(bx1[i], Y.zw, d);
            d = __builtin_elementwise_fma(bx2[i], Z.zw, d);
            m[i] = fminf(fminf(m[i], d.x), d.y);
        }
    }

    // Race-free partial-min store (coalesced per i).
#pragma unroll
    for (int i = 0; i < RSRC; ++i) {
        const int s = sb * SRC_PER_BLK + i * TPB + t;
        ws[(size_t)c * NMIN + s] = m[i];
    }
}

// Reduce, 8-way parallel per source: thread (s, k=octet) min-reduces chunks
// [8k, 8k+8), octets combine via shfl_xor(width 8), k==0 lane adds x^2,
// clamps, then block-sum + one atomicAdd.
__global__ __launch_bounds__(TPB) void chamfer_reduce(
        const float* __restrict__ ws,
        const float* __restrict__ src,
        float* __restrict__ out) {
    const int gid = blockIdx.x * TPB + threadIdx.x;
    const int s = gid >> 3;           // source id
    const int k = gid & 7;            // chunk octet

    float m = ws[(size_t)(k * 8) * NMIN + s];
#pragma unroll
    for (int j = 1; j < 8; ++j)
        m = fminf(m, ws[(size_t)(k * 8 + j) * NMIN + s]);

    // min across the 8 octet lanes (aligned groups of 8 within the wave)
#pragma unroll
    for (int off = 4; off > 0; off >>= 1)
        m = fminf(m, __shfl_xor(m, off, 8));

    float r = 0.0f;
    if (k == 0) {
        const float* p = src + (size_t)s * D;
        const float xs = p[0] * p[0] + p[1] * p[1] + p[2] * p[2];
        r = fmaxf(m + xs, 0.0f);
    }

#pragma unroll
    for (int off = 32; off > 0; off >>= 1)
        r += __shfl_down(r, off, 64);
    __shared__ float sred[TPB / 64];
    const int lane = threadIdx.x & 63;
    const int w    = threadIdx.x >> 6;
    if (lane == 0) sred[w] = r;
    __syncthreads();
    if (threadIdx.x == 0) {
        float acc = 0.0f;
#pragma unroll
        for (int i = 0; i < TPB / 64; ++i) acc += sred[i];
        atomicAdd(out, acc * (1.0f / N_BATCH));  // batch_reduction='mean'
    }
}

extern "C" void kernel_launch(void* const* d_in, const int* in_sizes, int n_in,
                              void* d_out, int out_size, void* d_ws, size_t ws_size,
                              hipStream_t stream) {
    const float* src = (const float*)d_in[0];  // (4, 8192, 3) f32
    const float* tgt = (const float*)d_in[1];  // (4, 8192, 3) f32
    float* out = (float*)d_out;                // scalar f32
    float* ws  = (float*)d_ws;                 // 64 * 32768 * 4B = 8 MB

    const int nblocks = NSB * NCHUNK;          // 32*64 = 2048 (8 per CU)
    chamfer_main<<<nblocks, TPB, 0, stream>>>(src, tgt, ws, out);

    chamfer_reduce<<<NMIN * 8 / TPB, TPB, 0, stream>>>(ws, src, out);
}